// Round 4
// baseline (1941.148 us; speedup 1.0000x reference)
//
#include <hip/hip_runtime.h>

// Problem constants (fixed by the reference)
#define D        64
#define V        1024
#define HQ       4
#define M_TOTAL  131072      // 32 * 4096 rows
#define MR       128         // rows per block
#define NV       128         // codes per chunk
#define NCHUNK   (V / NV)    // 8
#define NT       256         // threads per block
#define TAU      2e-3f       // near-tie rescue threshold (fast-path fp32 err ~1e-5)
#define LOSS_SCALE (1.25f / 8388608.0f)

// ---- ordered-float <-> uint transforms (ascending float == ascending uint) ----
__device__ __forceinline__ unsigned int f2ord(float f) {
  unsigned int b = __float_as_uint(f);
  return b ^ (((unsigned int)((int)b >> 31)) | 0x80000000u);
}
__device__ __forceinline__ float ord2f(unsigned int u) {
  unsigned int b = u ^ ((~((unsigned int)((int)u >> 31))) | 0x80000000u);
  return __uint_as_float(b);
}

// ---- prep: transpose codebook to WT[hq][d][v], compute W2[hq][v], zero loss ----
__global__ void vq_prep(const float* __restrict__ emb, float* __restrict__ WT,
                        float* __restrict__ W2, float* __restrict__ out) {
  int t = blockIdx.x * NT + threadIdx.x;   // over HQ*V = 4096
  if (blockIdx.x == 0 && threadIdx.x == 0) out[0] = 0.0f;
  if (t < HQ * V) {
    int i = t >> 10;          // stage
    int v = t & (V - 1);
    const float* e = emb + (size_t)t * D;
    float s = 0.0f;
    #pragma unroll
    for (int d = 0; d < D; ++d) {
      float w = e[d];
      s += w * w;
      WT[((size_t)i * D + d) * V + v] = w;
    }
    W2[t] = s;
  }
}

// ---- main kernel: 128 rows per block, all 4 stages fused ----
__launch_bounds__(NT, 1)
__global__ void vq_main(const float* __restrict__ latent,
                        const float* __restrict__ emb,
                        const float* __restrict__ WT,
                        const float* __restrict__ W2,
                        float* __restrict__ out) {
  __shared__ float Rt[D][MR + 4];          // residual tile, d-major, padded
  __shared__ float Wt[D][NV + 4];          // codebook chunk, d-major, padded
  __shared__ float W2s[NV];
  __shared__ unsigned long long redp[MR][16];  // packed (ord(m1)<<32 | idx)
  __shared__ unsigned int      redm2[MR][16];  // ord(m2)
  __shared__ int idx_lds[MR];
  __shared__ int n_rescue;
  __shared__ int rescue_rows[MR];
  __shared__ float resc_d2f[NT];
  __shared__ int   resc_ixs[NT];
  __shared__ float loss_red[NT];

  const int t  = threadIdx.x;
  const int tx = t & 15;        // code-tile coord  (8 codes)
  const int ty = t >> 4;        // row-tile coord   (8 rows)
  const int row0 = blockIdx.x * MR;

  // ---- load latent tile into Rt (coalesced global reads; LDS scatter once) ----
  for (int k = 0; k < 32; ++k) {
    int idx = t + k * NT;                  // 0..8191
    float vle = latent[(size_t)row0 * D + idx];
    int row = idx >> 6, dd = idx & 63;
    Rt[dd][row] = vle;
  }

  float loss_acc = 0.0f;

  for (int stage = 0; stage < HQ; ++stage) {
    float m1[8], m2f_[8];
    int   i1[8];
    #pragma unroll
    for (int i = 0; i < 8; ++i) { m1[i] = INFINITY; m2f_[i] = INFINITY; i1[i] = 0; }

    const float4* wtg4 = (const float4*)WT + (size_t)stage * D * V / 4;
    const float*  w2g  = W2 + stage * V;

    for (int chunk = 0; chunk < NCHUNK; ++chunk) {
      __syncthreads();   // Wt free to overwrite; Rt updates from prev stage visible
      // stage Wt chunk: 64 x 128 floats = 2048 float4, 8 per thread
      #pragma unroll
      for (int k = 0; k < 8; ++k) {
        int i4 = t + k * NT;               // 0..2047
        int d  = i4 >> 5, c4 = i4 & 31;
        float4 w = wtg4[d * (V / 4) + chunk * (NV / 4) + c4];
        *(float4*)&Wt[d][c4 * 4] = w;
      }
      if (t < NV / 4) {
        *(float4*)&W2s[t * 4] = ((const float4*)(w2g + chunk * NV))[t];
      }
      __syncthreads();

      // compute 8x8 register tile of r . W
      float acc[8][8];
      #pragma unroll
      for (int i = 0; i < 8; ++i)
        #pragma unroll
        for (int j = 0; j < 8; ++j) acc[i][j] = 0.0f;

      for (int d = 0; d < D; ++d) {
        float4 a0 = *(const float4*)&Rt[d][ty * 8];
        float4 a1 = *(const float4*)&Rt[d][ty * 8 + 4];
        float4 b0 = *(const float4*)&Wt[d][tx * 8];
        float4 b1 = *(const float4*)&Wt[d][tx * 8 + 4];
        float a[8] = {a0.x, a0.y, a0.z, a0.w, a1.x, a1.y, a1.z, a1.w};
        float b[8] = {b0.x, b0.y, b0.z, b0.w, b1.x, b1.y, b1.z, b1.w};
        #pragma unroll
        for (int i = 0; i < 8; ++i)
          #pragma unroll
          for (int j = 0; j < 8; ++j) acc[i][j] += a[i] * b[j];
      }

      // distances + top-2 tracking (codes ascend with j and chunk -> first-min ties)
      int cbase = chunk * NV + tx * 8;
      #pragma unroll
      for (int j = 0; j < 8; ++j) {
        float w2v = W2s[tx * 8 + j];
        int code = cbase + j;
        #pragma unroll
        for (int i = 0; i < 8; ++i) {
          float s = w2v - 2.0f * acc[i][j];
          if (s < m1[i]) { m2f_[i] = m1[i]; m1[i] = s; i1[i] = code; }
          else if (s < m2f_[i]) m2f_[i] = s;
        }
      }
    } // chunks

    // ---- block-level top-2 reduction per row ----
    #pragma unroll
    for (int i = 0; i < 8; ++i) {
      redp[ty * 8 + i][tx] = ((unsigned long long)f2ord(m1[i]) << 32) | (unsigned int)i1[i];
      redm2[ty * 8 + i][tx] = f2ord(m2f_[i]);
    }
    if (t == 0) n_rescue = 0;
    __syncthreads();

    if (t < MR) {
      unsigned long long bp = redp[t][0];
      unsigned int b2u = redm2[t][0];
      #pragma unroll
      for (int k = 1; k < 16; ++k) {
        unsigned long long p = redp[t][k];
        if (p < bp) { unsigned int old1 = (unsigned int)(bp >> 32); if (old1 < b2u) b2u = old1; bp = p; }
        else { unsigned int v1 = (unsigned int)(p >> 32); if (v1 < b2u) b2u = v1; }
        unsigned int v2 = redm2[t][k];
        if (v2 < b2u) b2u = v2;
      }
      idx_lds[t] = (int)(bp & 0xFFFFFFFFull);
      float m1f = ord2f((unsigned int)(bp >> 32));
      float m2f = ord2f(b2u);
      if (m2f - m1f < TAU) {
        int slot = atomicAdd(&n_rescue, 1);
        rescue_rows[slot] = t;
      }
    }
    __syncthreads();

    // ---- near-tie rescue: emulate the reference fp32 arithmetic ----
    // Hypothesis (R4): reference dot comes from a GEMM microkernel (OpenBLAS
    // sgemm via np.einsum optimize=True, or XLA-CPU/Eigen gebp) — each C
    // element is ONE sequential FMA chain over k ascending:
    //     c = fma(a_k, b_k, c),  k = 0..63
    // rr, w2: numpy pairwise-8 scalar accumulators (AVX512 host, n=64 < 128):
    //     ((r0+r1)+(r2+r3))+((r4+r5)+(r6+r7))
    // d2 = fl32( fl32(rr - 2*dot) + w2 )   (2*dot exact)
    // argmin: strict < ascending v -> first index on bit-equal (np/XLA argmin).
    int nres = n_rescue;
    for (int rr_i = 0; rr_i < nres; ++rr_i) {
      int row = rescue_rows[rr_i];
      // rr term (row-constant): pairwise-8 over fl(r_d^2)
      float p[8];
      #pragma unroll
      for (int j = 0; j < 8; ++j) p[j] = __fmul_rn(Rt[j][row], Rt[j][row]);
      #pragma unroll
      for (int i = 1; i < 8; ++i)
        #pragma unroll
        for (int j = 0; j < 8; ++j)
          p[j] = __fadd_rn(p[j], __fmul_rn(Rt[8 * i + j][row], Rt[8 * i + j][row]));
      float rrow = __fadd_rn(__fadd_rn(__fadd_rn(p[0], p[1]), __fadd_rn(p[2], p[3])),
                             __fadd_rn(__fadd_rn(p[4], p[5]), __fadd_rn(p[6], p[7])));

      const float* eb = emb + (size_t)stage * V * D;
      float bestd = INFINITY; int besti = 0;
      #pragma unroll
      for (int c = 0; c < 4; ++c) {
        int v = t * 4 + c;                 // ascending v per thread
        const float* wv = eb + (size_t)v * D;

        // dot: sequential FMA chain, k ascending (GEMM-microkernel order)
        float dot = 0.0f;
        #pragma unroll
        for (int d = 0; d < D; ++d)
          dot = __fmaf_rn(Rt[d][row], wv[d], dot);

        // w2: pairwise-8 emulation over fl(w_d^2)
        float q[8];
        #pragma unroll
        for (int j = 0; j < 8; ++j) q[j] = __fmul_rn(wv[j], wv[j]);
        #pragma unroll
        for (int i = 1; i < 8; ++i)
          #pragma unroll
          for (int j = 0; j < 8; ++j)
            q[j] = __fadd_rn(q[j], __fmul_rn(wv[8 * i + j], wv[8 * i + j]));
        float w2e = __fadd_rn(__fadd_rn(__fadd_rn(q[0], q[1]), __fadd_rn(q[2], q[3])),
                              __fadd_rn(__fadd_rn(q[4], q[5]), __fadd_rn(q[6], q[7])));

        float d2 = __fadd_rn(__fsub_rn(rrow, __fmul_rn(2.0f, dot)), w2e);
        if (d2 < bestd) { bestd = d2; besti = v; }   // strict < : first-index ties
      }
      resc_d2f[t] = bestd; resc_ixs[t] = besti;
      __syncthreads();
      if (t == 0) {
        float bd = resc_d2f[0]; int bi = resc_ixs[0];
        for (int k = 1; k < NT; ++k) {
          if (resc_d2f[k] < bd) { bd = resc_d2f[k]; bi = resc_ixs[k]; }
        }
        idx_lds[row] = bi;
      }
      __syncthreads();
    }

    // ---- update: r -= q; loss += r_new^2 ----
    {
      int row = t & (MR - 1);
      int d0  = (t >> 7) * 32;
      int code = idx_lds[row];
      const float4* qp = (const float4*)(emb + (((size_t)stage * V + code) * D + d0));
      #pragma unroll
      for (int k = 0; k < 8; ++k) {
        float4 q = qp[k];
        int dd = d0 + k * 4;
        float r0 = Rt[dd + 0][row] - q.x;
        float r1 = Rt[dd + 1][row] - q.y;
        float r2 = Rt[dd + 2][row] - q.z;
        float r3 = Rt[dd + 3][row] - q.w;
        Rt[dd + 0][row] = r0; Rt[dd + 1][row] = r1;
        Rt[dd + 2][row] = r2; Rt[dd + 3][row] = r3;
        loss_acc += r0 * r0 + r1 * r1 + r2 * r2 + r3 * r3;
      }
    }
    // next stage's chunk-0 __syncthreads() protects Rt reads-after-write
  } // stages

  __syncthreads();

  // ---- epilogue: quantised = latent - r_final (coalesced dword stores at out+1) ----
  for (int k = 0; k < 32; ++k) {
    int idx = t + k * NT;                  // 0..8191
    int row = idx >> 6, dd = idx & 63;
    float l = latent[(size_t)row0 * D + idx];
    out[1 + (size_t)row0 * D + idx] = l - Rt[dd][row];
  }

  // ---- loss reduction + atomic ----
  loss_red[t] = loss_acc;
  __syncthreads();
  for (int s = NT / 2; s > 0; s >>= 1) {
    if (t < s) loss_red[t] += loss_red[t + s];
    __syncthreads();
  }
  if (t == 0) atomicAdd(out, loss_red[0] * LOSS_SCALE);
}

extern "C" void kernel_launch(void* const* d_in, const int* in_sizes, int n_in,
                              void* d_out, int out_size, void* d_ws, size_t ws_size,
                              hipStream_t stream) {
  const float* latent = (const float*)d_in[0];
  const float* emb    = (const float*)d_in[1];
  float* out = (float*)d_out;

  float* WT = (float*)d_ws;                         // HQ*D*V floats = 1 MB
  float* W2 = WT + (size_t)HQ * D * V;              // HQ*V floats = 16 KB

  vq_prep<<<(HQ * V + NT - 1) / NT, NT, 0, stream>>>(emb, WT, W2, out);
  vq_main<<<M_TOTAL / MR, NT, 0, stream>>>(latent, emb, WT, W2, out);
}

// Round 5
// 710.455 us; speedup vs baseline: 2.7323x; 2.7323x over previous
//
#include <hip/hip_runtime.h>

// Problem constants (fixed by the reference)
#define D        64
#define V        1024
#define HQ       4
#define M_TOTAL  131072      // 32 * 4096 rows
#define MR       128         // rows per block
#define NVC      128         // codes per chunk
#define NCHUNK   8
#define NT       256         // threads per block
#define TAU      4e-3f       // near-tie rescue threshold (bf16-split fast-path err <~6e-4)
#define LOSS_SCALE (1.25f / 8388608.0f)
#define RT_STRIDE 68         // 64 + 4 pad (keeps rows 16B-aligned: 68*4=272=17*16)

typedef __attribute__((ext_vector_type(8))) short short8;
typedef __attribute__((ext_vector_type(4))) float f32x4;

// ---- ordered-float <-> uint transforms (ascending float == ascending uint) ----
__device__ __forceinline__ unsigned int f2ord(float f) {
  unsigned int b = __float_as_uint(f);
  return b ^ (((unsigned int)((int)b >> 31)) | 0x80000000u);
}
__device__ __forceinline__ float ord2f(unsigned int u) {
  unsigned int b = u ^ ((~((unsigned int)((int)u >> 31))) | 0x80000000u);
  return __uint_as_float(b);
}
// bf16 round-to-nearest-even truncation
__device__ __forceinline__ unsigned short f2bf(float f) {
  unsigned int u = __float_as_uint(f);
  return (unsigned short)((u + 0x7fffu + ((u >> 16) & 1u)) >> 16);
}

// ---- prep: split codebook into bf16 hi/lo in MFMA-fragment order, w2, zero loss ----
// Fragment layout (16B units within a stage): unit = (((c*8+tt)*2+kk)*2+hl)*64 + lane,
// holding W[code=c*128+tt*16+(lane&15)][k=kk*32+(lane>>4)*8 + j], j=0..7 as bf16.
__global__ void vq_prep(const float* __restrict__ emb, unsigned short* __restrict__ Wfrag,
                        float* __restrict__ W2, float* __restrict__ out) {
  int t = blockIdx.x * NT + threadIdx.x;   // over HQ*V = 4096
  if (t == 0) out[0] = 0.0f;
  if (t >= HQ * V) return;
  int s = t >> 10, v = t & (V - 1);
  int c = v >> 7, tt = (v >> 4) & 7, cl = v & 15;
  const float* e = emb + (size_t)t * D;
  float w2 = 0.0f;
  for (int k = 0; k < D; ++k) {
    float f = e[k];
    w2 += f * f;
    unsigned short hb = f2bf(f);
    float fh = __uint_as_float((unsigned int)hb << 16);
    unsigned short lb = f2bf(f - fh);
    int kk = k >> 5, q = (k >> 3) & 3, j = k & 7;
    size_t base = ((size_t)((((s * 8 + c) * 8 + tt) * 2 + kk) * 2)) * 512
                + (size_t)(q * 16 + cl) * 8 + j;
    Wfrag[base]       = hb;   // hl = 0
    Wfrag[base + 512] = lb;   // hl = 1
  }
  W2[t] = w2;
}

// ---- main kernel: 128 rows/block, 4 waves, MFMA bf16-split distances ----
__launch_bounds__(NT, 2)
__global__ void vq_main(const float* __restrict__ latent,
                        const float* __restrict__ emb,
                        const unsigned short* __restrict__ Wfrag,
                        const float* __restrict__ W2,
                        float* __restrict__ out) {
  __shared__ float Rt[MR][RT_STRIDE];                  // 34.8 KB, fp32 residual, row-major
  __shared__ __align__(16) unsigned short Wlds[16384]; // 32 KB code chunk (frag order)
  __shared__ float w2s[NVC];
  __shared__ int idx_lds[MR];
  __shared__ int n_rescue;
  __shared__ int rescue_rows[MR];
  __shared__ float resc_d2f[NT];
  __shared__ int   resc_ixs[NT];
  __shared__ float loss_red[NT];

  const int t    = threadIdx.x;
  const int lane = t & 63;
  const int w    = t >> 6;       // wave id, handles rows [w*32, w*32+32)
  const int cl   = lane & 15;
  const int q    = lane >> 4;
  const size_t row0 = (size_t)blockIdx.x * MR;

  // ---- load latent tile -> Rt (coalesced float4; one row per wave-instruction) ----
  {
    const float4* lg = (const float4*)(latent + row0 * D);
    #pragma unroll
    for (int k = 0; k < 8; ++k) {
      int i4 = t + k * NT;                   // 0..2047 float4s
      int row = i4 >> 4, dd = (i4 & 15) * 4;
      *(float4*)&Rt[row][dd] = lg[i4];
    }
  }

  float loss_acc = 0.0f;

  for (int stage = 0; stage < HQ; ++stage) {
    __syncthreads();           // Rt ready (initial load or previous stage's update)
    if (t == 0) n_rescue = 0;  // consumed later this stage (after more syncs)

    // ---- build A fragments (bf16 hi/lo) from Rt ----
    // a_frag: A[m=lane&15][k=quad*8+j]; rows = w*32 + rt*16 + cl; k = kk*32 + q*8 + j
    short8 Ah[2][2], Al[2][2];
    #pragma unroll
    for (int rt = 0; rt < 2; ++rt)
      #pragma unroll
      for (int kk = 0; kk < 2; ++kk) {
        const float* rp = &Rt[w * 32 + rt * 16 + cl][kk * 32 + q * 8];
        short8 h, l;
        #pragma unroll
        for (int j = 0; j < 8; ++j) {
          float f = rp[j];
          unsigned short hb = f2bf(f);
          float fh = __uint_as_float((unsigned int)hb << 16);
          h[j] = (short)hb;
          l[j] = (short)f2bf(f - fh);
        }
        Ah[rt][kk] = h; Al[rt][kk] = l;
      }

    // per-lane top-2 state: slot (rt, reg) covers row = w*32 + rt*16 + q*4 + reg,
    // restricted to cols ≡ cl (mod 16)
    float m1[2][4], m2[2][4]; int i1[2][4];
    #pragma unroll
    for (int rt = 0; rt < 2; ++rt)
      #pragma unroll
      for (int r = 0; r < 4; ++r) { m1[rt][r] = INFINITY; m2[rt][r] = INFINITY; i1[rt][r] = 0; }

    const float4* wfg = (const float4*)(Wfrag + (size_t)stage * 131072);
    const float4* w2g = (const float4*)(W2 + stage * V);

    for (int chunk = 0; chunk < NCHUNK; ++chunk) {
      __syncthreads();                       // Wlds free to overwrite
      // stage 32 KB chunk: linear copy, coalesced 1KB per wave-instruction
      {
        float4* wl4 = (float4*)Wlds;
        #pragma unroll
        for (int k = 0; k < 8; ++k)
          wl4[t + k * NT] = wfg[chunk * 2048 + t + k * NT];
        if (t < 32) *(float4*)&w2s[t * 4] = w2g[chunk * 32 + t];
      }
      __syncthreads();

      #pragma unroll
      for (int tt = 0; tt < 8; ++tt) {
        const short8* wb = (const short8*)Wlds;
        // B frags: contiguous per instruction -> conflict-free ds_read_b128
        short8 Bh0 = wb[((tt * 2 + 0) * 2 + 0) * 64 + lane];
        short8 Bl0 = wb[((tt * 2 + 0) * 2 + 1) * 64 + lane];
        short8 Bh1 = wb[((tt * 2 + 1) * 2 + 0) * 64 + lane];
        short8 Bl1 = wb[((tt * 2 + 1) * 2 + 1) * 64 + lane];
        float w2v = w2s[tt * 16 + cl];
        int code = chunk * NVC + tt * 16 + cl;
        #pragma unroll
        for (int rt = 0; rt < 2; ++rt) {
          f32x4 C = {0.0f, 0.0f, 0.0f, 0.0f};
          C = __builtin_amdgcn_mfma_f32_16x16x32_bf16(Ah[rt][0], Bh0, C, 0, 0, 0);
          C = __builtin_amdgcn_mfma_f32_16x16x32_bf16(Ah[rt][1], Bh1, C, 0, 0, 0);
          C = __builtin_amdgcn_mfma_f32_16x16x32_bf16(Al[rt][0], Bh0, C, 0, 0, 0);
          C = __builtin_amdgcn_mfma_f32_16x16x32_bf16(Al[rt][1], Bh1, C, 0, 0, 0);
          C = __builtin_amdgcn_mfma_f32_16x16x32_bf16(Ah[rt][0], Bl0, C, 0, 0, 0);
          C = __builtin_amdgcn_mfma_f32_16x16x32_bf16(Ah[rt][1], Bl1, C, 0, 0, 0);
          // d2-equivalent s = w2 - 2*dot (rr is row-constant, irrelevant for argmin)
          #pragma unroll
          for (int r = 0; r < 4; ++r) {
            float s = fmaf(-2.0f, C[r], w2v);
            bool lt = s < m1[rt][r];
            m2[rt][r] = fminf(m2[rt][r], fmaxf(s, m1[rt][r]));  // new m2 (uses old m1)
            m1[rt][r] = fminf(m1[rt][r], s);
            i1[rt][r] = lt ? code : i1[rt][r];
          }
        }
      }
    } // chunks

    // ---- 16-lane butterfly top-2 reduction (cols of one row live in lanes 16q..16q+15) ----
    #pragma unroll
    for (int rt = 0; rt < 2; ++rt)
      #pragma unroll
      for (int r = 0; r < 4; ++r) {
        unsigned int phi = f2ord(m1[rt][r]);
        unsigned int plo = (unsigned int)i1[rt][r];
        unsigned int s2  = f2ord(m2[rt][r]);
        #pragma unroll
        for (int mask = 1; mask <= 8; mask <<= 1) {
          unsigned int ohi = (unsigned int)__shfl_xor((int)phi, mask, 16);
          unsigned int olo = (unsigned int)__shfl_xor((int)plo, mask, 16);
          unsigned int os2 = (unsigned int)__shfl_xor((int)s2, mask, 16);
          unsigned long long p  = ((unsigned long long)phi << 32) | plo;
          unsigned long long po = ((unsigned long long)ohi << 32) | olo;
          unsigned int hmax = phi > ohi ? phi : ohi;
          s2 = s2 < os2 ? s2 : os2;
          s2 = s2 < hmax ? s2 : hmax;
          unsigned long long pm = p < po ? p : po;   // ties -> smaller idx (first index)
          phi = (unsigned int)(pm >> 32); plo = (unsigned int)pm;
        }
        if (cl == 0) {
          int row = w * 32 + rt * 16 + q * 4 + r;
          idx_lds[row] = (int)plo;
          float gap = ord2f(s2) - ord2f(phi);
          if (gap < TAU) {
            int slot = atomicAdd(&n_rescue, 1);
            rescue_rows[slot] = row;
          }
        }
      }
    __syncthreads();   // idx_lds + rescue flags visible

    // ---- near-tie rescue: bit-exact numpy-reference emulation (verified R4) ----
    // dot: ONE sequential FMA chain over k ascending; rr,w2: pairwise-8 scalar accs;
    // d2 = fl32( fl32(rr - 2*dot) + w2 ); strict < ascending v -> first-index ties.
    int nres = n_rescue;
    for (int rr_i = 0; rr_i < nres; ++rr_i) {
      int row = rescue_rows[rr_i];
      float p8[8];
      #pragma unroll
      for (int j = 0; j < 8; ++j) p8[j] = __fmul_rn(Rt[row][j], Rt[row][j]);
      #pragma unroll
      for (int i = 1; i < 8; ++i)
        #pragma unroll
        for (int j = 0; j < 8; ++j)
          p8[j] = __fadd_rn(p8[j], __fmul_rn(Rt[row][8 * i + j], Rt[row][8 * i + j]));
      float rrow = __fadd_rn(__fadd_rn(__fadd_rn(p8[0], p8[1]), __fadd_rn(p8[2], p8[3])),
                             __fadd_rn(__fadd_rn(p8[4], p8[5]), __fadd_rn(p8[6], p8[7])));
      const float* eb = emb + (size_t)stage * V * D;
      float bestd = INFINITY; int besti = 0;
      #pragma unroll
      for (int c = 0; c < 4; ++c) {
        int v = t * 4 + c;                   // ascending v per thread
        const float* wv = eb + (size_t)v * D;
        float dot = 0.0f;
        #pragma unroll
        for (int d = 0; d < D; ++d) dot = __fmaf_rn(Rt[row][d], wv[d], dot);
        float q8[8];
        #pragma unroll
        for (int j = 0; j < 8; ++j) q8[j] = __fmul_rn(wv[j], wv[j]);
        #pragma unroll
        for (int i = 1; i < 8; ++i)
          #pragma unroll
          for (int j = 0; j < 8; ++j)
            q8[j] = __fadd_rn(q8[j], __fmul_rn(wv[8 * i + j], wv[8 * i + j]));
        float w2e = __fadd_rn(__fadd_rn(__fadd_rn(q8[0], q8[1]), __fadd_rn(q8[2], q8[3])),
                              __fadd_rn(__fadd_rn(q8[4], q8[5]), __fadd_rn(q8[6], q8[7])));
        float d2 = __fadd_rn(__fsub_rn(rrow, __fmul_rn(2.0f, dot)), w2e);
        if (d2 < bestd) { bestd = d2; besti = v; }
      }
      resc_d2f[t] = bestd; resc_ixs[t] = besti;
      __syncthreads();
      if (t == 0) {
        float bd = resc_d2f[0]; int bi = resc_ixs[0];
        for (int k = 1; k < NT; ++k)
          if (resc_d2f[k] < bd) { bd = resc_d2f[k]; bi = resc_ixs[k]; }
        idx_lds[row] = bi;
      }
      __syncthreads();
    }

    // ---- update: r -= q (exact fp32); loss += r_new^2 ----
    {
      int row = t >> 1, half = t & 1;
      int code = idx_lds[row];
      const float4* qp = (const float4*)(emb + (((size_t)stage * V + code) * D + half * 32));
      #pragma unroll
      for (int k = 0; k < 8; ++k) {
        float4 qv = qp[k];
        float* rp = &Rt[row][half * 32 + k * 4];
        float r0 = rp[0] - qv.x, r1 = rp[1] - qv.y, r2 = rp[2] - qv.z, r3 = rp[3] - qv.w;
        rp[0] = r0; rp[1] = r1; rp[2] = r2; rp[3] = r3;
        loss_acc += r0 * r0 + r1 * r1 + r2 * r2 + r3 * r3;
      }
    }
    // next stage-top __syncthreads() protects Rt reads-after-write
  } // stages

  __syncthreads();

  // ---- epilogue: quantised = latent - r_final (coalesced dword stores at out+1) ----
  for (int k = 0; k < 32; ++k) {
    int idx = t + k * NT;                    // 0..8191
    int row = idx >> 6, dd = idx & 63;
    float l = latent[row0 * D + idx];
    out[1 + row0 * D + idx] = l - Rt[row][dd];
  }

  // ---- loss reduction + atomic ----
  loss_red[t] = loss_acc;
  __syncthreads();
  for (int s = NT / 2; s > 0; s >>= 1) {
    if (t < s) loss_red[t] += loss_red[t + s];
    __syncthreads();
  }
  if (t == 0) atomicAdd(out, loss_red[0] * LOSS_SCALE);
}

extern "C" void kernel_launch(void* const* d_in, const int* in_sizes, int n_in,
                              void* d_out, int out_size, void* d_ws, size_t ws_size,
                              hipStream_t stream) {
  const float* latent = (const float*)d_in[0];
  const float* emb    = (const float*)d_in[1];
  float* out = (float*)d_out;

  unsigned short* Wfrag = (unsigned short*)d_ws;            // HQ*V*D*2 ushorts = 1 MB
  float* W2 = (float*)(Wfrag + (size_t)HQ * V * D * 2);     // HQ*V floats = 16 KB

  vq_prep<<<(HQ * V + NT - 1) / NT, NT, 0, stream>>>(emb, Wfrag, W2, out);
  vq_main<<<M_TOTAL / MR, NT, 0, stream>>>(latent, emb, Wfrag, W2, out);
}